// Round 6
// baseline (162.788 us; speedup 1.0000x reference)
//
#include <hip/hip_runtime.h>
#include <hip/hip_bf16.h>

// MHGAT: B=8, J=2048, C=256, K=32, H=8, D=32; M = B*J = 16384
// World: all float tensors fp32; nbr int32; out fp32.
// Round 6: vectorized attention phase-B gather (uint4 = 8 bf16 per load,
// 8-way k-split + padded LDS reduce). Everything else unchanged from r5:
// Wp folded into Wv (VP = x @ Weff from GEMM), register softmax, bf16 q/k/VP.

typedef short bf16x8 __attribute__((ext_vector_type(8)));
typedef float f32x4  __attribute__((ext_vector_type(4)));

__device__ __forceinline__ float bf2f(unsigned short u) {
    union { unsigned int i; float f; } c; c.i = ((unsigned int)u) << 16; return c.f;
}
__device__ __forceinline__ unsigned short f2bf(float f) {
    union { float f; unsigned int i; } c; c.f = f;
    unsigned int r = c.i + 0x7FFFu + ((c.i >> 16) & 1u);  // RNE
    return (unsigned short)(r >> 16);
}

__device__ __forceinline__ void gld_lds16(void* lds, const void* g) {
    __builtin_amdgcn_global_load_lds(
        (const __attribute__((address_space(1))) unsigned int*)g,
        (__attribute__((address_space(3))) unsigned int*)lds,
        16, 0, 0);
}

// ---------------------------------------------------------------------------
// Prep: blocks [0,4096): x fp32 -> xb bf16. blocks [4096,4864): weights ->
//   Wt[0][n][k]=Wq[k][n], Wt[1][n][k]=Wk[k][n],
//   Wt[2][n][k]=Weff[k][n], Weff[k][h*32+c] = sum_d Wv[k][h*32+d]*Wp[h*32+d][c]
// ---------------------------------------------------------------------------
__global__ __launch_bounds__(256) void prep(
    const float* __restrict__ x,
    const float* __restrict__ Wq, const float* __restrict__ Wk,
    const float* __restrict__ Wv, const float* __restrict__ Wp,
    unsigned short* __restrict__ xb, unsigned short* __restrict__ Wt)
{
    const int blk = blockIdx.x, tid = threadIdx.x;
    if (blk < 4096) {
        int t = blk * 256 + tid;
        float4 f = ((const float4*)x)[t];
        ushort4 u;
        u.x = f2bf(f.x); u.y = f2bf(f.y); u.z = f2bf(f.z); u.w = f2bf(f.w);
        ((ushort4*)xb)[t] = u;
        return;
    }
    int wi = blk - 4096;
    int w = wi >> 8, n = wi & 255, t = tid;       // t = k index
    if (w == 0) {
        Wt[(size_t)n * 256 + t] = f2bf(Wq[(size_t)t * 256 + n]);
    } else if (w == 1) {
        Wt[(size_t)(256 + n) * 256 + t] = f2bf(Wk[(size_t)t * 256 + n]);
    } else {
        int h = n >> 5, c = n & 31;
        float acc = 0.f;
#pragma unroll
        for (int d = 0; d < 32; d++)
            acc += Wv[(size_t)t * 256 + h * 32 + d] * Wp[(size_t)(h * 32 + d) * 32 + c];
        Wt[(size_t)(512 + n) * 256 + t] = f2bf(acc);
    }
}

// ---------------------------------------------------------------------------
// QKV GEMM: xb[16384,256]bf16 @ Wt[z][n][k] -> bf16 [16384,256].
// BM=BN=128, BK=64, 4 waves (2x2), 4x4 frags of 16x16x32 MFMA, fp32 accum.
// z: 0->q, 1->k, 2->VP.
// ---------------------------------------------------------------------------
__global__ __launch_bounds__(256) void qkv_mfma(
    const unsigned short* __restrict__ xb,
    const unsigned short* __restrict__ Wt,
    unsigned short* __restrict__ Q, unsigned short* __restrict__ Kp,
    unsigned short* __restrict__ VP)
{
    __shared__ unsigned short Als[128][64];
    __shared__ unsigned short Bls[128][64];

    const unsigned short* Wb = Wt + (size_t)blockIdx.z * 65536;
    unsigned short* Y = (blockIdx.z == 0) ? Q : (blockIdx.z == 1) ? Kp : VP;

    const int row0 = blockIdx.x * 128;
    const int col0 = blockIdx.y * 128;
    const int tid  = threadIdx.x;
    const int w    = tid >> 6, l = tid & 63;
    const int wm   = (w >> 1) * 64, wn = (w & 1) * 64;
    const int lm   = l & 15, quad = l >> 4;

    f32x4 acc[4][4];
#pragma unroll
    for (int i = 0; i < 4; i++)
#pragma unroll
        for (int j = 0; j < 4; j++) acc[i][j] = (f32x4){0.f, 0.f, 0.f, 0.f};

    const char* Ab = (const char*)(xb + (size_t)row0 * 256);
    const char* Bb = (const char*)(Wb + (size_t)col0 * 256);

    for (int k0 = 0; k0 < 256; k0 += 64) {
#pragma unroll
        for (int i = 0; i < 4; i++) {
            int s = i * 256 + tid;
            int r = s >> 3, c = s & 7;
            size_t go = (size_t)r * 512 + (size_t)k0 * 2 + c * 16;
            gld_lds16((char*)Als + s * 16, Ab + go);
            gld_lds16((char*)Bls + s * 16, Bb + go);
        }
        __syncthreads();

#pragma unroll
        for (int kk = 0; kk < 64; kk += 32) {
            bf16x8 a[4], b[4];
#pragma unroll
            for (int tm = 0; tm < 4; tm++)
                a[tm] = *(const bf16x8*)&Als[wm + tm * 16 + lm][kk + quad * 8];
#pragma unroll
            for (int tn = 0; tn < 4; tn++)
                b[tn] = *(const bf16x8*)&Bls[wn + tn * 16 + lm][kk + quad * 8];
#pragma unroll
            for (int tm = 0; tm < 4; tm++)
#pragma unroll
                for (int tn = 0; tn < 4; tn++)
                    acc[tm][tn] = __builtin_amdgcn_mfma_f32_16x16x32_bf16(
                        a[tm], b[tn], acc[tm][tn], 0, 0, 0);
        }
        __syncthreads();
    }

    // C/D layout: col=lane&15, row=quad*4+reg (m89-verified). bf16 stores.
#pragma unroll
    for (int tm = 0; tm < 4; tm++) {
        int rbase = row0 + wm + tm * 16 + quad * 4;
#pragma unroll
        for (int tn = 0; tn < 4; tn++) {
            int col = col0 + wn + tn * 16 + lm;
#pragma unroll
            for (int r = 0; r < 4; r++)
                Y[(size_t)(rbase + r) * 256 + col] = f2bf(acc[tm][tn][r]);
        }
    }
}

// ---------------------------------------------------------------------------
// Attention: one 256-thread block per (b,j). XCD swizzle b = blk&7.
// Phase A (lane=(kk,h)): score + softmax via half-wave shfl butterflies.
// Phase B (thread=(h,c8,ks)): 8-way k-split, uint4 (8x bf16) gather loads,
//   two-stage padded-LDS reduction (conflict-free).
// ---------------------------------------------------------------------------
__global__ __launch_bounds__(256) void attn_all(
    const unsigned short* __restrict__ qb,   // [16384,256] bf16
    const unsigned short* __restrict__ kb,   // [16384,256] bf16
    const unsigned short* __restrict__ vp,   // [16384,256] bf16 (VP)
    const int*            __restrict__ nbr,  // [16384,32]
    float*                __restrict__ out)  // [16384,32] fp32
{
    __shared__ int   koff[32];        // nb * 256 (element offset)
    __shared__ float pw[8 * 33];      // [h][kk], +1 pad
    __shared__ float redB[8 * 32 * 9];// [h][c][ks], stride 9 (conflict-free)
    __shared__ float red2[8 * 33];    // [h][c], +1 pad

    const int b   = blockIdx.x & 7;
    const int j   = blockIdx.x >> 3;
    const int bj  = (b << 11) + j;
    const int tid = threadIdx.x;

    if (tid < 32) koff[tid] = nbr[(size_t)bj * 32 + tid] << 8;
    __syncthreads();

    const int wv = tid >> 6, l = tid & 63;
    const int h  = 2 * wv + (l >> 5);
    const int kk = l & 31;

    // q fragment (this lane's head) in registers.
    float qr[32];
    {
        const uint4* qp = (const uint4*)(qb + (size_t)bj * 256 + h * 32);
#pragma unroll
        for (int c4 = 0; c4 < 4; c4++) {
            uint4 u = qp[c4];
            const unsigned short* u8 = (const unsigned short*)&u;
#pragma unroll
            for (int t = 0; t < 8; t++) qr[c4 * 8 + t] = bf2f(u8[t]);
        }
    }

    // score: dot(q_h, k[nb_kk]_h)
    float s;
    {
        const unsigned short* kr =
            kb + (size_t)(b << 19) + koff[kk] + h * 32;  // b*2048*256
        float acc = 0.f;
#pragma unroll
        for (int c4 = 0; c4 < 4; c4++) {
            uint4 u = ((const uint4*)kr)[c4];
            const unsigned short* u8 = (const unsigned short*)&u;
#pragma unroll
            for (int t = 0; t < 8; t++) acc += qr[c4 * 8 + t] * bf2f(u8[t]);
        }
        s = acc * 0.17677669529663687f;   // 1/sqrt(32)
        s = (s > 0.f) ? s : 0.2f * s;     // leaky_relu 0.2
    }

    // softmax over kk within the 32-lane half-wave
    float mx = s;
#pragma unroll
    for (int m = 16; m >= 1; m >>= 1) mx = fmaxf(mx, __shfl_xor(mx, m));
    float e = __expf(s - mx);
    float sum = e;
#pragma unroll
    for (int m = 16; m >= 1; m >>= 1) sum += __shfl_xor(sum, m);
    pw[h * 33 + kk] = e / sum;
    __syncthreads();

    // Phase B: thread = (h2, c8, ks). Each: 4 k-iters x uint4 (8 bf16).
    {
        const int h2 = tid >> 5;
        const int c8 = (tid >> 3) & 3;
        const int ks = tid & 7;
        const unsigned short* vb2 = vp + (size_t)(b << 19) + h2 * 32 + c8 * 8;
        float acc[8] = {};
#pragma unroll
        for (int ii = 0; ii < 4; ii++) {
            int i = ks * 4 + ii;
            float wgt = pw[h2 * 33 + i];
            uint4 u = *(const uint4*)(vb2 + koff[i]);
            const unsigned short* u8 = (const unsigned short*)&u;
#pragma unroll
            for (int e2 = 0; e2 < 8; e2++) acc[e2] += wgt * bf2f(u8[e2]);
        }
#pragma unroll
        for (int e2 = 0; e2 < 8; e2++)
            redB[(h2 * 32 + c8 * 8 + e2) * 9 + ks] = acc[e2];
    }
    __syncthreads();

    // stage 2: thread (h,c) sums over ks
    {
        const int c = tid & 31, hh = tid >> 5;
        float p = 0.f;
#pragma unroll
        for (int s2 = 0; s2 < 8; s2++) p += redB[(hh * 32 + c) * 9 + s2];
        red2[hh * 33 + c] = p;
    }
    __syncthreads();

    if (tid < 32) {
        float o = 0.f;
#pragma unroll
        for (int i = 0; i < 8; i++) o += red2[i * 33 + tid];
        out[(size_t)bj * 32 + tid] = o;
    }
}

// ---------------------------------------------------------------------------
// Tier 0 fallback (tiny ws): fully fused fp32, zero workspace. Slow, correct.
// ---------------------------------------------------------------------------
__global__ __launch_bounds__(256) void fused_all(
    const float* __restrict__ X, const int* __restrict__ nbr,
    const float* __restrict__ Wq, const float* __restrict__ Wk,
    const float* __restrict__ Wv, const float* __restrict__ Wp,
    float* __restrict__ out)
{
    __shared__ float xr[256], qrow[256], xn[256];
    __shared__ float vn[32][256];
    __shared__ int   nb[32];
    __shared__ float sc[32][8], pwv[32][8];
    __shared__ float sp[256], hd[256];
    __shared__ float red[8][32];

    const int bj = blockIdx.x, b = bj >> 11, tid = threadIdx.x;

    xr[tid] = X[(size_t)bj * 256 + tid];
    if (tid < 32) nb[tid] = nbr[(size_t)bj * 32 + tid];
    __syncthreads();

    {
        float acc = 0.f;
#pragma unroll 8
        for (int c = 0; c < 256; c++) acc += xr[c] * Wq[(size_t)c * 256 + tid];
        qrow[tid] = acc;
    }
    __syncthreads();

    for (int i = 0; i < 32; i++) {
        size_t r = (size_t)(b * 2048 + nb[i]);
        xn[tid] = X[r * 256 + tid];
        __syncthreads();
        float ka = 0.f, va = 0.f;
#pragma unroll 8
        for (int c = 0; c < 256; c++) {
            float xc = xn[c];
            ka += xc * Wk[(size_t)c * 256 + tid];
            va += xc * Wv[(size_t)c * 256 + tid];
        }
        vn[i][tid] = va;
        sp[tid] = qrow[tid] * ka;
        __syncthreads();
        if (tid < 8) {
            float s = 0.f;
#pragma unroll
            for (int d = 0; d < 32; d++) s += sp[tid * 32 + d];
            s *= 0.17677669529663687f;
            s = (s > 0.f) ? s : 0.2f * s;
            sc[i][tid] = s;
        }
        __syncthreads();
    }

    {
        const int h = tid & 7, kk = tid >> 3;
        float mx = -1e30f;
#pragma unroll
        for (int i = 0; i < 32; i++) mx = fmaxf(mx, sc[i][h]);
        float ssum = 0.f;
#pragma unroll
        for (int i = 0; i < 32; i++) ssum += __expf(sc[i][h] - mx);
        pwv[kk][h] = __expf(sc[kk][h] - mx) / ssum;
    }
    __syncthreads();

    {
        const int h2 = tid >> 5;
        float acc = 0.f;
#pragma unroll 8
        for (int i = 0; i < 32; i++) acc += pwv[i][h2] * vn[i][tid];
        hd[tid] = acc;
    }
    __syncthreads();

    {
        const int c = tid & 31, ch = tid >> 5;
        float p = 0.f;
#pragma unroll
        for (int i = 0; i < 32; i++) { int r = ch * 32 + i; p += hd[r] * Wp[r * 32 + c]; }
        red[ch][c] = p;
    }
    __syncthreads();

    if (tid < 32) {
        float o = 0.f;
#pragma unroll
        for (int i = 0; i < 8; i++) o += red[i][tid];
        out[(size_t)bj * 32 + tid] = o;
    }
}

extern "C" void kernel_launch(void* const* d_in, const int* in_sizes, int n_in,
                              void* d_out, int out_size, void* d_ws, size_t ws_size,
                              hipStream_t stream) {
    const float* x   = (const float*)d_in[0];
    const int*   nbr = (const int*)d_in[1];
    const float* Wq  = (const float*)d_in[2];
    const float* Wk  = (const float*)d_in[3];
    const float* Wv  = (const float*)d_in[4];
    const float* Wp  = (const float*)d_in[5];
    float*       out = (float*)d_out;

    const size_t ME   = (size_t)16384 * 256;
    const size_t need = (4 * ME + 3 * 65536) * sizeof(unsigned short);  // ~34 MB

    if (ws_size >= need) {
        unsigned short* q  = (unsigned short*)d_ws;
        unsigned short* k  = q + ME;
        unsigned short* vp = k + ME;
        unsigned short* xb = vp + ME;
        unsigned short* Wt = xb + ME;

        prep<<<4096 + 768, 256, 0, stream>>>(x, Wq, Wk, Wv, Wp, xb, Wt);
        qkv_mfma<<<dim3(128, 2, 3), 256, 0, stream>>>(xb, Wt, q, k, vp);
        attn_all<<<16384, 256, 0, stream>>>(q, k, vp, nbr, out);
    } else {
        fused_all<<<16384, 256, 0, stream>>>(x, nbr, Wq, Wk, Wv, Wp, out);
    }
}